// Round 6
// baseline (112.655 us; speedup 1.0000x reference)
//
#include <hip/hip_runtime.h>
#include <hip/hip_bf16.h>

namespace {

constexpr int D = 4096;
constexpr int NT = 256;
constexpr int ROWS = 8;  // rows per persistent block; grid = B/ROWS = 2048

// XOR swizzle on the logical dword index. Sources {bit5, bit8, bit9} are
// disjoint from targets {bit2, bit3, bit4} -> involution, stays in [0,4096),
// preserves 4-dword aligned quads (b128-compatible).
// Bank math (bank = dword addr mod 32):
//  R1 write (i=16t+4q+c): quad bank-group (t0^t4, q1^t5, q0^t1) -> uniform 8/group.
//  R2 r/w  (i=256a+16k+b): bank = (k0^a0, b3^a1, b2^k1, b1, b0) -> 2-way, free.
//  R3 r/w  (i=256k+t):    bank = (t4^k0, t3^k1, t2^t5, t1, t0) -> 2-way, free.
//  R4 read (i=4t+1024m+c): quad bank-group (t2^t6, t1^t7, t0^t3) -> uniform 8/group.
__device__ __forceinline__ int swz(int i) {
    return i ^ (((i >> 8) & 1) << 4) ^ (((i >> 9) & 1) << 3) ^ (((i >> 5) & 1) << 2);
}

__device__ __forceinline__ void fwht16(float v[16]) {
#pragma unroll
    for (int h = 1; h < 16; h <<= 1) {
#pragma unroll
        for (int g = 0; g < 16; g += (h << 1)) {
#pragma unroll
            for (int j = 0; j < h; ++j) {
                const float a = v[g + j];
                const float b = v[g + j + h];
                v[g + j] = a + b;
                v[g + j + h] = a - b;
            }
        }
    }
}

__global__ __launch_bounds__(NT) void rht_kernel(const float* __restrict__ x,
                                                 const float* __restrict__ signs,
                                                 float* __restrict__ out,
                                                 int nrows) {
    __shared__ float lds[D];  // 16 KiB
    const int t = threadIdx.x;
    const int row0 = blockIdx.x * ROWS;
    if (row0 >= nrows) return;
    const int nr = min(ROWS, nrows - row0);

    // signs slice for this thread's R1 ownership (i = 16t+k), kept in VGPRs
    // across all rows (signs is identical for every row).
    float sv[16];
    {
        const float4* __restrict__ s4 = reinterpret_cast<const float4*>(signs) + (t << 2);
#pragma unroll
        for (int q = 0; q < 4; ++q) {
            const float4 s = s4[q];
            sv[4 * q + 0] = s.x;
            sv[4 * q + 1] = s.y;
            sv[4 * q + 2] = s.z;
            sv[4 * q + 3] = s.w;
        }
    }

    // Prefetch row 0 into registers.
    float4 nxt[4];
    {
        const float4* __restrict__ x4 =
            reinterpret_cast<const float4*>(x + (size_t)row0 * D) + (t << 2);
#pragma unroll
        for (int q = 0; q < 4; ++q) nxt[q] = x4[q];
    }

#pragma unroll 1
    for (int r = 0; r < nr; ++r) {
        float* __restrict__ outr = out + (size_t)(row0 + r) * D;

        // ---- consume prefetched row: v = x * signs (frees nxt for reuse)
        float v[16];
#pragma unroll
        for (int q = 0; q < 4; ++q) {
            v[4 * q + 0] = nxt[q].x * sv[4 * q + 0];
            v[4 * q + 1] = nxt[q].y * sv[4 * q + 1];
            v[4 * q + 2] = nxt[q].z * sv[4 * q + 2];
            v[4 * q + 3] = nxt[q].w * sv[4 * q + 3];
        }

        // ---- issue next row's loads NOW; latency hides under R1..R4 below.
        if (r + 1 < nr) {
            const float4* __restrict__ x4 =
                reinterpret_cast<const float4*>(x + (size_t)(row0 + r + 1) * D) + (t << 2);
#pragma unroll
            for (int q = 0; q < 4; ++q) nxt[q] = x4[q];
        }

        // ---- Round 1: bits 0-3 in registers (i = 16t+k), b128 LDS writes.
        fwht16(v);
#pragma unroll
        for (int q = 0; q < 4; ++q) {
            *reinterpret_cast<float4*>(&lds[swz((t << 4) + (q << 2))]) =
                make_float4(v[4 * q], v[4 * q + 1], v[4 * q + 2], v[4 * q + 3]);
        }
        __syncthreads();

        // ---- Round 2: bits 4-7 (i = 256a + 16k + b). Same-thread r/w.
        {
            const int b2 = ((t >> 4) << 8) + (t & 15);
#pragma unroll
            for (int k = 0; k < 16; ++k) v[k] = lds[swz(b2 + (k << 4))];
            fwht16(v);
#pragma unroll
            for (int k = 0; k < 16; ++k) lds[swz(b2 + (k << 4))] = v[k];
        }
        __syncthreads();

        // ---- Round 3: bits 8-11 (i = 256k + t). Write back for R4 regroup.
        {
#pragma unroll
            for (int k = 0; k < 16; ++k) v[k] = lds[swz((k << 8) + t)];
            fwht16(v);
#pragma unroll
            for (int k = 0; k < 16; ++k) lds[swz((k << 8) + t)] = v[k];
        }
        __syncthreads();

        // ---- Round 4: regroup to contiguous quads (i = 4t + 1024m), b128
        // LDS reads + float4 global stores (1 KiB/wave-instr).
#pragma unroll
        for (int m = 0; m < 4; ++m) {
            float4 w = *reinterpret_cast<const float4*>(&lds[swz((t << 2) + (m << 10))]);
            w.x *= 0.015625f;  // 1/sqrt(4096)
            w.y *= 0.015625f;
            w.z *= 0.015625f;
            w.w *= 0.015625f;
            *reinterpret_cast<float4*>(&outr[(t << 2) + (m << 10)]) = w;
        }
        __syncthreads();  // LDS reuse guard before next row's R1 writes
    }
}

}  // namespace

extern "C" void kernel_launch(void* const* d_in, const int* in_sizes, int n_in,
                              void* d_out, int out_size, void* d_ws, size_t ws_size,
                              hipStream_t stream) {
    const float* x = (const float*)d_in[0];
    const float* signs = (const float*)d_in[1];
    float* out = (float*)d_out;
    const int B = in_sizes[0] / D;  // 16384 rows
    const int grid = (B + ROWS - 1) / ROWS;
    rht_kernel<<<dim3(grid), dim3(NT), 0, stream>>>(x, signs, out, B);
}

// Round 7
// 99.293 us; speedup vs baseline: 1.1346x; 1.1346x over previous
//
#include <hip/hip_runtime.h>
#include <hip/hip_bf16.h>

namespace {

constexpr int D = 4096;
constexpr int NT = 512;  // 2 rows per block, side by side (waves 0-3 / 4-7)

// XOR swizzle on the logical dword index. Sources {bit5, bit8, bit9} are
// disjoint from targets {bit2, bit3, bit4} -> involution, stays in [0,4096),
// preserves 4-dword aligned quads (b128-compatible).
// Bank math (bank = dword addr mod 32), per 256-thread row-group:
//  R1 write (i=16t+4q+c): quad bank-group (t0^t4, q1^t5, q0^t1) -> uniform 8/group.
//  R2 r/w  (i=256a+16k+b): bank = (k0^a0, b3^a1, b2^k1, b1, b0) -> 2-way, free.
//  R3 r/w  (i=256k+t):    bank = (t4^k0, t3^k1, t2^t5, t1, t0) -> 2-way, free.
//  R4 read (i=4t+1024m+c): quad bank-group (t2^t6, t1^t7, t0^t3) -> uniform 8/group.
// Row-half base h*4096 is bank- and alignment-neutral (4096 % 32 == 0).
__device__ __forceinline__ int swz(int i) {
    return i ^ (((i >> 8) & 1) << 4) ^ (((i >> 9) & 1) << 3) ^ (((i >> 5) & 1) << 2);
}

__device__ __forceinline__ void fwht16(float v[16]) {
#pragma unroll
    for (int h = 1; h < 16; h <<= 1) {
#pragma unroll
        for (int g = 0; g < 16; g += (h << 1)) {
#pragma unroll
            for (int j = 0; j < h; ++j) {
                const float a = v[g + j];
                const float b = v[g + j + h];
                v[g + j] = a + b;
                v[g + j + h] = a - b;
            }
        }
    }
}

__global__ __launch_bounds__(NT) void rht_kernel(const float* __restrict__ x,
                                                 const float* __restrict__ signs,
                                                 float* __restrict__ out) {
    __shared__ float lds[2 * D];  // 32 KiB, one 16 KiB half per row
    const int t = threadIdx.x & 255;   // index within this row's 256-thread group
    const int h = threadIdx.x >> 8;    // which of the block's 2 rows
    float* __restrict__ ldsr = &lds[h * D];
    const size_t row = (size_t)blockIdx.x * 2 + h;
    const float* __restrict__ xr = x + row * (size_t)D;
    float* __restrict__ outr = out + row * (size_t)D;

    float v[16];

    // ---- Round 1: thread owns i = 16t + k (bits 0-3). float4 loads,
    // 1 KiB contiguous per wave instruction.
    {
        const float4* __restrict__ x4 = reinterpret_cast<const float4*>(xr) + (t << 2);
        const float4* __restrict__ s4 = reinterpret_cast<const float4*>(signs) + (t << 2);
#pragma unroll
        for (int q = 0; q < 4; ++q) {
            const float4 a = x4[q];
            const float4 s = s4[q];
            v[4 * q + 0] = a.x * s.x;
            v[4 * q + 1] = a.y * s.y;
            v[4 * q + 2] = a.z * s.z;
            v[4 * q + 3] = a.w * s.w;
        }
    }
    fwht16(v);
#pragma unroll
    for (int q = 0; q < 4; ++q) {
        *reinterpret_cast<float4*>(&ldsr[swz((t << 4) + (q << 2))]) =
            make_float4(v[4 * q], v[4 * q + 1], v[4 * q + 2], v[4 * q + 3]);
    }
    __syncthreads();

    // ---- Round 2: thread owns i = (t>>4)*256 + 16k + (t&15) (bits 4-7).
    // Same-thread read+write of its own 16 slots -> no barrier inside.
    {
        const int b2 = ((t >> 4) << 8) + (t & 15);
#pragma unroll
        for (int k = 0; k < 16; ++k) v[k] = ldsr[swz(b2 + (k << 4))];
        fwht16(v);
#pragma unroll
        for (int k = 0; k < 16; ++k) ldsr[swz(b2 + (k << 4))] = v[k];
    }
    __syncthreads();

    // ---- Round 3: thread owns i = 256k + t (bits 8-11). Write back for the
    // R4 regroup so global stores can be wide.
    {
#pragma unroll
        for (int k = 0; k < 16; ++k) v[k] = ldsr[swz((k << 8) + t)];
        fwht16(v);
#pragma unroll
        for (int k = 0; k < 16; ++k) ldsr[swz((k << 8) + t)] = v[k];
    }
    __syncthreads();

    // ---- Round 4: regroup to contiguous quads (i = 4t + 1024m), b128 LDS
    // reads + float4 global stores (1 KiB contiguous per wave instruction).
#pragma unroll
    for (int m = 0; m < 4; ++m) {
        float4 w = *reinterpret_cast<const float4*>(&ldsr[swz((t << 2) + (m << 10))]);
        w.x *= 0.015625f;  // 1/sqrt(4096)
        w.y *= 0.015625f;
        w.z *= 0.015625f;
        w.w *= 0.015625f;
        *reinterpret_cast<float4*>(&outr[(t << 2) + (m << 10)]) = w;
    }
}

}  // namespace

extern "C" void kernel_launch(void* const* d_in, const int* in_sizes, int n_in,
                              void* d_out, int out_size, void* d_ws, size_t ws_size,
                              hipStream_t stream) {
    const float* x = (const float*)d_in[0];
    const float* signs = (const float*)d_in[1];
    float* out = (float*)d_out;
    const int B = in_sizes[0] / D;  // 16384 rows (even)
    rht_kernel<<<dim3(B / 2), dim3(NT), 0, stream>>>(x, signs, out);
}

// Round 8
// 98.576 us; speedup vs baseline: 1.1428x; 1.0073x over previous
//
#include <hip/hip_runtime.h>
#include <hip/hip_bf16.h>

namespace {

constexpr int D = 4096;
constexpr int NT = 256;

// Per-wave chunk-local swizzle on the 10-bit dword index: XOR j's bits {7,8,9}
// into bits {2,3,4}. Involution, bits 0-1 untouched (quads stay b128-able).
// Bank math (bank = phys bits 0-4), per wave (64 lanes, 32 banks, 2-way free):
//  A write quads j=L<<4|q<<2: group(2,3,4) = (q0^L3, q1^L4, L0^L5)
//     -> per-q uniform 8 lanes/group (b128-optimal).
//  B r/w scalar j=(L&15)|k<<4|(L>>4)<<8: bank = (L0,L1,L2^k3,L3^L4,k0^L5)
//     -> exact 2-way uniform (free).
//  C r/w quads j=L<<2|m<<8: group = (L0^L5, L1^m0, L2^m1) -> per-m uniform 8/group.
//  S2 read quads j=t<<2 in chunk w: group = (L0^L5, L1^t6, L2^t7)
//     -> per-(w,instr) uniform 8 lanes/group.
__device__ __forceinline__ int swzc(int j) {
    return j ^ (((j >> 7) & 7) << 2);
}

__device__ __forceinline__ void fwht16(float v[16]) {
#pragma unroll
    for (int h = 1; h < 16; h <<= 1) {
#pragma unroll
        for (int g = 0; g < 16; g += (h << 1)) {
#pragma unroll
            for (int j = 0; j < h; ++j) {
                const float a = v[g + j];
                const float b = v[g + j + h];
                v[g + j] = a + b;
                v[g + j + h] = a - b;
            }
        }
    }
}

// Wave-local fence: all prior LDS writes retired, and the compiler may not
// move LDS ops across. No block rendezvous (cheap vs s_barrier).
__device__ __forceinline__ void wave_lds_fence() {
    asm volatile("s_waitcnt lgkmcnt(0)" ::: "memory");
    __builtin_amdgcn_wave_barrier();
}

__global__ __launch_bounds__(NT) void rht_kernel(const float* __restrict__ x,
                                                 const float* __restrict__ signs,
                                                 float* __restrict__ out) {
    __shared__ float lds[D];  // 16 KiB; wave w owns chunk [w*1024, w*1024+1024)
    const int t = threadIdx.x;
    const int L = t & 63;                       // lane
    float* __restrict__ chunk = &lds[(t >> 6) << 10];
    const size_t row = blockIdx.x;
    const float* __restrict__ xr = x + row * (size_t)D;
    float* __restrict__ outr = out + row * (size_t)D;

    float v[16];

    // ---- Load + signs. Thread owns global i = 16t + k -> chunk-local
    // j = 16L + k. float4 loads, 1 KiB contiguous per wave instruction.
    {
        const float4* __restrict__ x4 = reinterpret_cast<const float4*>(xr) + (t << 2);
        const float4* __restrict__ s4 = reinterpret_cast<const float4*>(signs) + (t << 2);
#pragma unroll
        for (int q = 0; q < 4; ++q) {
            const float4 a = x4[q];
            const float4 s = s4[q];
            v[4 * q + 0] = a.x * s.x;
            v[4 * q + 1] = a.y * s.y;
            v[4 * q + 2] = a.z * s.z;
            v[4 * q + 3] = a.w * s.w;
        }
    }

    // ---- Round A: bits 0-3 in registers; b128 writes to own wave's chunk.
    fwht16(v);
#pragma unroll
    for (int q = 0; q < 4; ++q) {
        *reinterpret_cast<float4*>(&chunk[swzc((L << 4) | (q << 2))]) =
            make_float4(v[4 * q], v[4 * q + 1], v[4 * q + 2], v[4 * q + 3]);
    }
    wave_lds_fence();

    // ---- Round B: bits 4-7. Lane owns j = (L&15) | k<<4 | (L>>4)<<8.
    // In-place r/w of its own 16 slots (wave-internal exchange only).
    {
        const int bb = (L & 15) | ((L >> 4) << 8);
#pragma unroll
        for (int k = 0; k < 16; ++k) v[k] = chunk[swzc(bb | (k << 4))];
        fwht16(v);
#pragma unroll
        for (int k = 0; k < 16; ++k) chunk[swzc(bb | (k << 4))] = v[k];
    }
    wave_lds_fence();

    // ---- Round C: bits 8-9. Lane owns quads j = L<<2 | m<<8 (m=0..3,
    // c=0..3 inside quad). b128 read, 4-point FWHT over m per c, b128 write.
    {
#pragma unroll
        for (int m = 0; m < 4; ++m) {
            const float4 a =
                *reinterpret_cast<const float4*>(&chunk[swzc((L << 2) | (m << 8))]);
            v[4 * m + 0] = a.x;
            v[4 * m + 1] = a.y;
            v[4 * m + 2] = a.z;
            v[4 * m + 3] = a.w;
        }
#pragma unroll
        for (int c = 0; c < 4; ++c) {
            const float a0 = v[c], a1 = v[4 + c], a2 = v[8 + c], a3 = v[12 + c];
            const float b0 = a0 + a1, b1 = a0 - a1, b2 = a2 + a3, b3 = a2 - a3;
            v[c] = b0 + b2;
            v[4 + c] = b1 + b3;
            v[8 + c] = b0 - b2;
            v[12 + c] = b1 - b3;
        }
#pragma unroll
        for (int m = 0; m < 4; ++m) {
            *reinterpret_cast<float4*>(&chunk[swzc((L << 2) | (m << 8))]) =
                make_float4(v[4 * m], v[4 * m + 1], v[4 * m + 2], v[4 * m + 3]);
        }
    }
    __syncthreads();  // the ONLY block-wide barrier

    // ---- Stage 2: bits 10-11 across the 4 wave chunks, fused with the
    // store regroup. Thread owns i = 4t + 1024*w2: b128 LDS reads, 4-point
    // FWHT over w2, scale, float4 global stores (1 KiB/wave-instr).
    {
        float4 g[4];
        const int jq = swzc(t << 2);
#pragma unroll
        for (int w2 = 0; w2 < 4; ++w2)
            g[w2] = *reinterpret_cast<const float4*>(&lds[(w2 << 10) | jq]);

        float4 b0, b1, b2, b3;
        b0.x = g[0].x + g[1].x; b1.x = g[0].x - g[1].x;
        b2.x = g[2].x + g[3].x; b3.x = g[2].x - g[3].x;
        b0.y = g[0].y + g[1].y; b1.y = g[0].y - g[1].y;
        b2.y = g[2].y + g[3].y; b3.y = g[2].y - g[3].y;
        b0.z = g[0].z + g[1].z; b1.z = g[0].z - g[1].z;
        b2.z = g[2].z + g[3].z; b3.z = g[2].z - g[3].z;
        b0.w = g[0].w + g[1].w; b1.w = g[0].w - g[1].w;
        b2.w = g[2].w + g[3].w; b3.w = g[2].w - g[3].w;

        const float sc = 0.015625f;  // 1/sqrt(4096)
        float4 o;
        o.x = (b0.x + b2.x) * sc; o.y = (b0.y + b2.y) * sc;
        o.z = (b0.z + b2.z) * sc; o.w = (b0.w + b2.w) * sc;
        *reinterpret_cast<float4*>(&outr[(t << 2)]) = o;
        o.x = (b1.x + b3.x) * sc; o.y = (b1.y + b3.y) * sc;
        o.z = (b1.z + b3.z) * sc; o.w = (b1.w + b3.w) * sc;
        *reinterpret_cast<float4*>(&outr[(t << 2) + 1024]) = o;
        o.x = (b0.x - b2.x) * sc; o.y = (b0.y - b2.y) * sc;
        o.z = (b0.z - b2.z) * sc; o.w = (b0.w - b2.w) * sc;
        *reinterpret_cast<float4*>(&outr[(t << 2) + 2048]) = o;
        o.x = (b1.x - b3.x) * sc; o.y = (b1.y - b3.y) * sc;
        o.z = (b1.z - b3.z) * sc; o.w = (b1.w - b3.w) * sc;
        *reinterpret_cast<float4*>(&outr[(t << 2) + 3072]) = o;
    }
}

}  // namespace

extern "C" void kernel_launch(void* const* d_in, const int* in_sizes, int n_in,
                              void* d_out, int out_size, void* d_ws, size_t ws_size,
                              hipStream_t stream) {
    const float* x = (const float*)d_in[0];
    const float* signs = (const float*)d_in[1];
    float* out = (float*)d_out;
    const int B = in_sizes[0] / D;  // 16384 rows
    rht_kernel<<<dim3(B), dim3(NT), 0, stream>>>(x, signs, out);
}

// Round 9
// 96.303 us; speedup vs baseline: 1.1698x; 1.0236x over previous
//
#include <hip/hip_runtime.h>
#include <hip/hip_bf16.h>

namespace {

constexpr int D = 4096;
constexpr int NT = 256;

// XOR swizzle on the logical dword index (involution, preserves aligned quads).
// Bank math verified in R4/R5: R1 write uniform-8/bank-group, R2 2-way,
// R3 2-way, R4 quad-read uniform-8/bank-group -> all conflict-free.
__device__ __forceinline__ int swz(int i) {
    return i ^ (((i >> 8) & 1) << 4) ^ (((i >> 9) & 1) << 3) ^ (((i >> 5) & 1) << 2);
}

__device__ __forceinline__ void fwht16(float v[16]) {
#pragma unroll
    for (int h = 1; h < 16; h <<= 1) {
#pragma unroll
        for (int g = 0; g < 16; g += (h << 1)) {
#pragma unroll
            for (int j = 0; j < h; ++j) {
                const float a = v[g + j];
                const float b = v[g + j + h];
                v[g + j] = a + b;
                v[g + j + h] = a - b;
            }
        }
    }
}

// R5-proven per-row pipeline: v already sign-multiplied; 4 LDS rounds,
// 3 internal barriers, vectorized global stores.
__device__ __forceinline__ void row_rounds(float v[16], float* __restrict__ lds,
                                           float* __restrict__ outr, int t) {
    // ---- Round 1: bits 0-3 in registers (i = 16t+k), b128 LDS writes.
    fwht16(v);
#pragma unroll
    for (int q = 0; q < 4; ++q) {
        *reinterpret_cast<float4*>(&lds[swz((t << 4) + (q << 2))]) =
            make_float4(v[4 * q], v[4 * q + 1], v[4 * q + 2], v[4 * q + 3]);
    }
    __syncthreads();

    // ---- Round 2: bits 4-7 (i = 256a + 16k + b). Same-thread r/w.
    {
        const int b2 = ((t >> 4) << 8) + (t & 15);
#pragma unroll
        for (int k = 0; k < 16; ++k) v[k] = lds[swz(b2 + (k << 4))];
        fwht16(v);
#pragma unroll
        for (int k = 0; k < 16; ++k) lds[swz(b2 + (k << 4))] = v[k];
    }
    __syncthreads();

    // ---- Round 3: bits 8-11 (i = 256k + t). Write back for R4 regroup.
    {
#pragma unroll
        for (int k = 0; k < 16; ++k) v[k] = lds[swz((k << 8) + t)];
        fwht16(v);
#pragma unroll
        for (int k = 0; k < 16; ++k) lds[swz((k << 8) + t)] = v[k];
    }
    __syncthreads();

    // ---- Round 4: regroup to contiguous quads (i = 4t + 1024m), b128 LDS
    // reads + float4 global stores (1 KiB contiguous per wave instruction).
#pragma unroll
    for (int m = 0; m < 4; ++m) {
        float4 w = *reinterpret_cast<const float4*>(&lds[swz((t << 2) + (m << 10))]);
        w.x *= 0.015625f;  // 1/sqrt(4096)
        w.y *= 0.015625f;
        w.z *= 0.015625f;
        w.w *= 0.015625f;
        *reinterpret_cast<float4*>(&outr[(t << 2) + (m << 10)]) = w;
    }
}

__global__ __launch_bounds__(NT) void rht_kernel(const float* __restrict__ x,
                                                 const float* __restrict__ signs,
                                                 float* __restrict__ out) {
    __shared__ float lds[D];  // 16 KiB
    const int t = threadIdx.x;
    const size_t r0 = (size_t)blockIdx.x * 2;

    // ---- Head: issue ALL global loads back-to-back (signs, row0, row1) so
    // the block pays ONE memory latency for two rows of work.
    float v0[16], v1[16];
    {
        const float4* __restrict__ s4 = reinterpret_cast<const float4*>(signs) + (t << 2);
        const float4* __restrict__ a4 =
            reinterpret_cast<const float4*>(x + r0 * D) + (t << 2);
        const float4* __restrict__ b4 =
            reinterpret_cast<const float4*>(x + (r0 + 1) * D) + (t << 2);
        float4 sv[4], a0[4], a1[4];
#pragma unroll
        for (int q = 0; q < 4; ++q) sv[q] = s4[q];
#pragma unroll
        for (int q = 0; q < 4; ++q) a0[q] = a4[q];
#pragma unroll
        for (int q = 0; q < 4; ++q) a1[q] = b4[q];
        // Multiply both rows now; sv dies here (peak live ~56 VGPR).
#pragma unroll
        for (int q = 0; q < 4; ++q) {
            v0[4 * q + 0] = a0[q].x * sv[q].x;
            v0[4 * q + 1] = a0[q].y * sv[q].y;
            v0[4 * q + 2] = a0[q].z * sv[q].z;
            v0[4 * q + 3] = a0[q].w * sv[q].w;
            v1[4 * q + 0] = a1[q].x * sv[q].x;
            v1[4 * q + 1] = a1[q].y * sv[q].y;
            v1[4 * q + 2] = a1[q].z * sv[q].z;
            v1[4 * q + 3] = a1[q].w * sv[q].w;
        }
    }

    // ---- Row 0 (v1 parked in registers), then row 1.
    row_rounds(v0, lds, out + r0 * D, t);
    __syncthreads();  // LDS reuse guard between rows
    row_rounds(v1, lds, out + (r0 + 1) * D, t);
}

}  // namespace

extern "C" void kernel_launch(void* const* d_in, const int* in_sizes, int n_in,
                              void* d_out, int out_size, void* d_ws, size_t ws_size,
                              hipStream_t stream) {
    const float* x = (const float*)d_in[0];
    const float* signs = (const float*)d_in[1];
    float* out = (float*)d_out;
    const int B = in_sizes[0] / D;  // 16384 rows (even)
    rht_kernel<<<dim3(B / 2), dim3(NT), 0, stream>>>(x, signs, out);
}

// Round 10
// 96.141 us; speedup vs baseline: 1.1718x; 1.0017x over previous
//
#include <hip/hip_runtime.h>
#include <hip/hip_bf16.h>

namespace {

constexpr int D = 4096;
constexpr int NT = 256;

// XOR swizzle on the logical dword index. Sources {bit5, bit8, bit9} are
// disjoint from targets {bit2, bit3, bit4} -> bijection (involution), result
// stays in [0, 4096). Bits [1:0] untouched -> 4-dword aligned quads remain
// contiguous, so b128 LDS ops survive.
// Bank math (bank = dword addr mod 32):
//  R1 write (i = 16t+4q+c): quad bank-group (t0^t4, q1^t5, q0^t1)
//      -> uniform 8 lanes/group (optimal b128).
//  R2 r/w  (i = 256a+16k+b): bank = (k0^a0, b3^a1, b2^k1, b1, b0) -> 2-way, free.
//  R3 r/w  (i = 256k+t):    bank = (t4^k0, t3^k1, t2^t5, t1, t0) -> 2-way, free.
//  R4 read (i = 4t+1024m+c): quad bank-group (t2^t6, t1^t7, t0^t3)
//      -> uniform 8 lanes/group (optimal b128).
__device__ __forceinline__ int swz(int i) {
    return i ^ (((i >> 8) & 1) << 4) ^ (((i >> 9) & 1) << 3) ^ (((i >> 5) & 1) << 2);
}

__device__ __forceinline__ void fwht16(float v[16]) {
#pragma unroll
    for (int h = 1; h < 16; h <<= 1) {
#pragma unroll
        for (int g = 0; g < 16; g += (h << 1)) {
#pragma unroll
            for (int j = 0; j < h; ++j) {
                const float a = v[g + j];
                const float b = v[g + j + h];
                v[g + j] = a + b;
                v[g + j + h] = a - b;
            }
        }
    }
}

__global__ __launch_bounds__(NT) void rht_kernel(const float* __restrict__ x,
                                                 const float* __restrict__ signs,
                                                 float* __restrict__ out) {
    __shared__ float lds[D];  // 16 KiB
    const int t = threadIdx.x;
    const size_t row = blockIdx.x;
    const float* __restrict__ xr = x + row * (size_t)D;
    float* __restrict__ outr = out + row * (size_t)D;

    float v[16];

    // ---- Round 1: thread owns i = 16t + k (bits 0-3). float4 loads,
    // 1 KiB contiguous per wave instruction.
    {
        const float4* __restrict__ x4 = reinterpret_cast<const float4*>(xr) + (t << 2);
        const float4* __restrict__ s4 = reinterpret_cast<const float4*>(signs) + (t << 2);
#pragma unroll
        for (int q = 0; q < 4; ++q) {
            const float4 a = x4[q];
            const float4 s = s4[q];
            v[4 * q + 0] = a.x * s.x;
            v[4 * q + 1] = a.y * s.y;
            v[4 * q + 2] = a.z * s.z;
            v[4 * q + 3] = a.w * s.w;
        }
    }
    fwht16(v);
#pragma unroll
    for (int q = 0; q < 4; ++q) {
        *reinterpret_cast<float4*>(&lds[swz((t << 4) + (q << 2))]) =
            make_float4(v[4 * q], v[4 * q + 1], v[4 * q + 2], v[4 * q + 3]);
    }
    __syncthreads();

    // ---- Round 2: thread owns i = (t>>4)*256 + 16k + (t&15) (bits 4-7).
    // Same-thread read+write of its own 16 slots -> no barrier inside.
    {
        const int b2 = ((t >> 4) << 8) + (t & 15);
#pragma unroll
        for (int k = 0; k < 16; ++k) v[k] = lds[swz(b2 + (k << 4))];
        fwht16(v);
#pragma unroll
        for (int k = 0; k < 16; ++k) lds[swz(b2 + (k << 4))] = v[k];
    }
    __syncthreads();

    // ---- Round 3: thread owns i = 256k + t (bits 8-11). Results go back to
    // LDS (same slots, same thread) so R4 can store vectorized.
    {
#pragma unroll
        for (int k = 0; k < 16; ++k) v[k] = lds[swz((k << 8) + t)];
        fwht16(v);
#pragma unroll
        for (int k = 0; k < 16; ++k) lds[swz((k << 8) + t)] = v[k];
    }
    __syncthreads();

    // ---- Round 4: pure regroup. Thread reads 4 aligned quads i = 4t + 1024m
    // (b128, bank-uniform) and stores float4 -> 1 KiB contiguous per wave
    // instruction on the global write path.
#pragma unroll
    for (int m = 0; m < 4; ++m) {
        float4 w = *reinterpret_cast<const float4*>(&lds[swz((t << 2) + (m << 10))]);
        w.x *= 0.015625f;  // 1/sqrt(4096)
        w.y *= 0.015625f;
        w.z *= 0.015625f;
        w.w *= 0.015625f;
        *reinterpret_cast<float4*>(&outr[(t << 2) + (m << 10)]) = w;
    }
}

}  // namespace

extern "C" void kernel_launch(void* const* d_in, const int* in_sizes, int n_in,
                              void* d_out, int out_size, void* d_ws, size_t ws_size,
                              hipStream_t stream) {
    const float* x = (const float*)d_in[0];
    const float* signs = (const float*)d_in[1];
    float* out = (float*)d_out;
    const int B = in_sizes[0] / D;  // 16384 rows
    rht_kernel<<<dim3(B), dim3(NT), 0, stream>>>(x, signs, out);
}

// Round 11
// 80.236 us; speedup vs baseline: 1.4041x; 1.1982x over previous
//
#include <hip/hip_runtime.h>
#include <hip/hip_bf16.h>

namespace {

constexpr int D = 4096;
constexpr int NT = 256;

// Native clang vector type — the nontemporal builtins reject HIP's struct float4.
typedef float fvec4 __attribute__((ext_vector_type(4)));

// XOR swizzle on the logical dword index. Sources {bit5, bit8, bit9} are
// disjoint from targets {bit2, bit3, bit4} -> bijection (involution), result
// stays in [0, 4096). Bits [1:0] untouched -> 4-dword aligned quads remain
// contiguous, so b128 LDS ops survive.
// Bank math (bank = dword addr mod 32):
//  R1 write (i = 16t+4q+c): quad bank-group (t0^t4, q1^t5, q0^t1)
//      -> uniform 8 lanes/group (optimal b128).
//  R2 r/w  (i = 256a+16k+b): bank = (k0^a0, b3^a1, b2^k1, b1, b0) -> 2-way, free.
//  R3 r/w  (i = 256k+t):    bank = (t4^k0, t3^k1, t2^t5, t1, t0) -> 2-way, free.
//  R4 read (i = 4t+1024m+c): quad bank-group (t2^t6, t1^t7, t0^t3)
//      -> uniform 8 lanes/group (optimal b128).
__device__ __forceinline__ int swz(int i) {
    return i ^ (((i >> 8) & 1) << 4) ^ (((i >> 9) & 1) << 3) ^ (((i >> 5) & 1) << 2);
}

__device__ __forceinline__ void fwht16(float v[16]) {
#pragma unroll
    for (int h = 1; h < 16; h <<= 1) {
#pragma unroll
        for (int g = 0; g < 16; g += (h << 1)) {
#pragma unroll
            for (int j = 0; j < h; ++j) {
                const float a = v[g + j];
                const float b = v[g + j + h];
                v[g + j] = a + b;
                v[g + j + h] = a - b;
            }
        }
    }
}

__global__ __launch_bounds__(NT) void rht_kernel(const float* __restrict__ x,
                                                 const float* __restrict__ signs,
                                                 float* __restrict__ out) {
    __shared__ float lds[D];  // 16 KiB
    const int t = threadIdx.x;
    const size_t row = blockIdx.x;
    const float* __restrict__ xr = x + row * (size_t)D;
    float* __restrict__ outr = out + row * (size_t)D;

    float v[16];

    // ---- Round 1: thread owns i = 16t + k (bits 0-3). Cached float4 loads,
    // 1 KiB contiguous per wave instruction.
    {
        const float4* __restrict__ x4 = reinterpret_cast<const float4*>(xr) + (t << 2);
        const float4* __restrict__ s4 = reinterpret_cast<const float4*>(signs) + (t << 2);
#pragma unroll
        for (int q = 0; q < 4; ++q) {
            const float4 a = x4[q];
            const float4 s = s4[q];
            v[4 * q + 0] = a.x * s.x;
            v[4 * q + 1] = a.y * s.y;
            v[4 * q + 2] = a.z * s.z;
            v[4 * q + 3] = a.w * s.w;
        }
    }
    fwht16(v);
#pragma unroll
    for (int q = 0; q < 4; ++q) {
        *reinterpret_cast<float4*>(&lds[swz((t << 4) + (q << 2))]) =
            make_float4(v[4 * q], v[4 * q + 1], v[4 * q + 2], v[4 * q + 3]);
    }
    __syncthreads();

    // ---- Round 2: thread owns i = (t>>4)*256 + 16k + (t&15) (bits 4-7).
    // Same-thread read+write of its own 16 slots -> no barrier inside.
    {
        const int b2 = ((t >> 4) << 8) + (t & 15);
#pragma unroll
        for (int k = 0; k < 16; ++k) v[k] = lds[swz(b2 + (k << 4))];
        fwht16(v);
#pragma unroll
        for (int k = 0; k < 16; ++k) lds[swz(b2 + (k << 4))] = v[k];
    }
    __syncthreads();

    // ---- Round 3: thread owns i = 256k + t (bits 8-11). Results go back to
    // LDS (same slots, same thread) so R4 can store vectorized.
    {
#pragma unroll
        for (int k = 0; k < 16; ++k) v[k] = lds[swz((k << 8) + t)];
        fwht16(v);
#pragma unroll
        for (int k = 0; k < 16; ++k) lds[swz((k << 8) + t)] = v[k];
    }
    __syncthreads();

    // ---- Round 4: regroup to contiguous quads (i = 4t + 1024m), b128 LDS
    // reads; NONTEMPORAL float4 stores (full 64B lines per wave, evict-first
    // in L2 so the write stream doesn't evict inbound read lines).
#pragma unroll
    for (int m = 0; m < 4; ++m) {
        float4 w = *reinterpret_cast<const float4*>(&lds[swz((t << 2) + (m << 10))]);
        fvec4 o;
        o.x = w.x * 0.015625f;  // 1/sqrt(4096)
        o.y = w.y * 0.015625f;
        o.z = w.z * 0.015625f;
        o.w = w.w * 0.015625f;
        __builtin_nontemporal_store(o,
            reinterpret_cast<fvec4*>(&outr[(t << 2) + (m << 10)]));
    }
}

}  // namespace

extern "C" void kernel_launch(void* const* d_in, const int* in_sizes, int n_in,
                              void* d_out, int out_size, void* d_ws, size_t ws_size,
                              hipStream_t stream) {
    const float* x = (const float*)d_in[0];
    const float* signs = (const float*)d_in[1];
    float* out = (float*)d_out;
    const int B = in_sizes[0] / D;  // 16384 rows
    rht_kernel<<<dim3(B), dim3(NT), 0, stream>>>(x, signs, out);
}